// Round 11
// baseline (301.998 us; speedup 1.0000x reference)
//
#include <hip/hip_runtime.h>

// (B,H,Lq,Lkv) = (2,32,2048,2048), KEEP_RATIO=0.5, SINK=4, RECENT=64, ALPHA=0.2
#define B_   2
#define H_   32
#define BH   64
#define LQ   2048
#define LKV  2048
#define SINKN   4
#define RECENTN 64
#define MID  1980                              // LKV - SINK - RECENT
#define TOTAL_BUDGET 30592                     // (1024-68)*32
#define MINB 198                               // int(1980*0.5*0.2)
#define QCH  8                                 // q-chunks  (grid: 2*8*64 = 1024 blocks)
#define KVCH 2
#define KVLEN (LKV / KVCH)                     // 1024 cols per block
#define QLEN (LQ / QCH)                        // 256 rows per block
#define TROWS 4                                // rows per LDS tile
#define NT   (QLEN / TROWS)                    // 64 tiles
#define JW   495                               // MID/4, j-window per countmask block

// Native v_log_f32 (log2, ~2^-21 rel err) — accuracy-safe (R3-R10 all absmax 0).
static __device__ __forceinline__ float fast_log2(float x) {
#if defined(__has_builtin) && __has_builtin(__builtin_amdgcn_logf)
  return __builtin_amdgcn_logf(x);
#else
  float r; asm volatile("v_log_f32 %0, %1" : "=v"(r) : "v"(x)); return r;
#endif
}

// Issue one 4-row tile via global_load_lds (HBM -> LDS, no VGPR return).
// ldsbase is wave-uniform (HW adds lane*16B). One wave covers 1KB of each 4KB row.
static __device__ __forceinline__ void issue_tile(const float* base, int tile,
                                                  float* ldsbase, int laneoff) {
#pragma unroll
  for (int r = 0; r < TROWS; ++r) {
    const float* g = base + (size_t)(tile * TROWS + r) * LKV + laneoff;
    __builtin_amdgcn_global_load_lds(
        (const __attribute__((address_space(1))) void*)g,
        (__attribute__((address_space(3))) void*)(ldsbase + r * 1024),
        16, 0, 0);
  }
}

// Stats pass, MAX-OUTSTANDING variant: triple-buffered prefetch-2 LDS-DMA
// pipeline (steady-state 8-12 outstanding 1KB loads per wave, counted vmcnt
// never drained mid-loop) x 3 blocks/CU x 12 waves -> ~96-144KB reads in
// flight per CU (~2.5-3x R10). Wave w loads bytes [w*1024,(w+1)*1024) of each
// row and reads back exactly that quarter (col-map == lane-map): barrier-free.
// f32 group-of-16-rows accumulation folded into f64, fixed order.
__global__ __launch_bounds__(256) void stats_kernel(const float* __restrict__ A,
                                                    double* __restrict__ spart,
                                                    double* __restrict__ epart) {
  const int kvc = blockIdx.x;     // 0..KVCH-1
  const int qc  = blockIdx.y;     // 0..QCH-1
  const int bh  = blockIdx.z;     // 0..63
  const int t   = threadIdx.x;    // 0..255
  const int w   = t >> 6;         // wave 0..3

  __shared__ float lbuf[3][TROWS][1024];   // 48 KB triple buffer
  __shared__ double red[256];

  const float* base = A + ((size_t)bh * LQ + (size_t)qc * QLEN) * LKV + kvc * KVLEN;
  const int laneoff = 4 * t;                 // = w*256 + lane*4 floats
  float* ldsw[3] = { &lbuf[0][0][w * 256], &lbuf[1][0][w * 256], &lbuf[2][0][w * 256] };

  double s0 = 0.0, s1 = 0.0, s2 = 0.0, s3 = 0.0, e = 0.0;
  float fs0 = 0.f, fs1 = 0.f, fs2 = 0.f, fs3 = 0.f;
  float fe0 = 0.f, fe1 = 0.f, fe2 = 0.f, fe3 = 0.f;

  issue_tile(base, 0, ldsw[0], laneoff);
  issue_tile(base, 1, ldsw[1], laneoff);
  int cur = 0, nxt = 2;   // nxt = buffer for tile+2
  for (int tile = 0; tile < NT; ++tile) {
    if (tile + 2 < NT) {
      issue_tile(base, tile + 2, ldsw[nxt], laneoff);
      asm volatile("s_waitcnt vmcnt(8)" ::: "memory");   // tile's 4 loads done; 8 in flight
    } else if (tile + 1 < NT) {
      asm volatile("s_waitcnt vmcnt(4)" ::: "memory");
    } else {
      asm volatile("s_waitcnt vmcnt(0)" ::: "memory");
    }
#pragma unroll
    for (int r = 0; r < TROWS; ++r) {
      float4 wv = *reinterpret_cast<const float4*>(&lbuf[cur][r][4 * t]);
      fs0 += wv.x; fs1 += wv.y; fs2 += wv.z; fs3 += wv.w;
      fe0 = fmaf(wv.x, fast_log2(wv.x + 1e-8f), fe0);
      fe1 = fmaf(wv.y, fast_log2(wv.y + 1e-8f), fe1);
      fe2 = fmaf(wv.z, fast_log2(wv.z + 1e-8f), fe2);
      fe3 = fmaf(wv.w, fast_log2(wv.w + 1e-8f), fe3);
    }
    if ((tile & 3) == 3) {  // every 16 rows: fold f32 -> f64 (fixed order)
      s0 += (double)fs0; s1 += (double)fs1; s2 += (double)fs2; s3 += (double)fs3;
      e += ((double)fe0 + (double)fe1) + ((double)fe2 + (double)fe3);
      fs0 = fs1 = fs2 = fs3 = 0.f;
      fe0 = fe1 = fe2 = fe3 = 0.f;
    }
    cur = (cur == 2) ? 0 : cur + 1;
    nxt = (nxt == 2) ? 0 : nxt + 1;
  }

  double* sp = spart + (size_t)(qc * BH + bh) * LKV + kvc * KVLEN + 4 * t;
  sp[0] = s0; sp[1] = s1; sp[2] = s2; sp[3] = s3;

  red[t] = e;
  __syncthreads();
  for (int off = 128; off > 0; off >>= 1) {
    if (t < off) red[t] += red[t + off];
    __syncthreads();
  }
  if (t == 0) epart[(size_t)bh * (QCH * KVCH) + qc * KVCH + kvc] = red[0];
}

// Fused budget + reduce + stable-descending rank + mask write (2-launch pipeline).
// Block (jc, bh): redundantly computes its batch's budget allocation (exact
// _head_budgets semantics: half-even rint, Python floor-div), builds s[0..MID)
// in LDS (fixed-order f64 sum of QCH partials), then broadcast-only i-scan
// ranks 2 j-slots per thread. rank(j)=#{i: s_i>s_j}+#{i<j: s_i==s_j}.
__global__ __launch_bounds__(256) void countmask_kernel(const double* __restrict__ spart,
                                                        const double* __restrict__ epart,
                                                        int* __restrict__ out) {
  const int jc = blockIdx.x, bh = blockIdx.y, t = threadIdx.x;
  __shared__ double s[MID];
  __shared__ double he[H_];
  __shared__ int bud[H_];
  __shared__ int ksh;

  for (int m = t; m < MID; m += 256) {
    double v = 0.0;
    for (int qc = 0; qc < QCH; ++qc)
      v += spart[(size_t)(qc * BH + bh) * LKV + SINKN + m];
    s[m] = v;
  }
  const int b = bh >> 5;   // batch of this head
  if (t < H_) {
    double ss = 0.0;
    for (int p = 0; p < QCH * KVCH; ++p)
      ss += epart[(size_t)(b * H_ + t) * (QCH * KVCH) + p];
    he[t] = (-0.6931471805599453 * ss) / (double)LQ;
  }
  __syncthreads();
  if (t == 0) {
    double S = 0.0;
    for (int h = 0; h < H_; ++h) S += he[h];
    S += 1e-8;
    long long sum = 0;
    for (int h = 0; h < H_; ++h) {
      double x = he[h] / S * (double)TOTAL_BUDGET;
      int v = (int)rint(x);          // jnp.round = half-to-even
      if (v < MINB) v = MINB;
      bud[h] = v; sum += v;
    }
    long long diff = (long long)TOTAL_BUDGET - sum;
    long long ph = (diff >= 0) ? diff / H_ : -((-diff + H_ - 1) / H_);
    long long rem = diff - ph * H_;
    const int h = bh & 31;
    long long v = (long long)bud[h] + ph + ((h < rem) ? 1 : 0);
    if (v < 1) v = 1;
    if (v > MID) v = MID;
    ksh = (int)v;
  }
  __syncthreads();

  const int j0 = jc * JW + t;            // max 3*495+255 = 1740 < MID
  const int j1 = j0 + 256;               // valid if t < JW-256 = 239
  const bool has1 = (t < JW - 256);
  const double k0 = s[j0];
  const double k1 = has1 ? s[j1] : 0.0;
  unsigned c0 = 0, c1 = 0;
  for (int i = 0; i < MID; ++i) {
    const double si = s[i];
    c0 += (si > k0) ? 1u : 0u;
    c0 += ((si == k0) && (i < j0)) ? 1u : 0u;
    c1 += (si > k1) ? 1u : 0u;
    c1 += ((si == k1) && (i < j1)) ? 1u : 0u;
  }
  const unsigned k = (unsigned)ksh;
  out[(size_t)bh * LKV + SINKN + j0] = (c0 < k) ? 1 : 0;
  if (has1) out[(size_t)bh * LKV + SINKN + j1] = (c1 < k) ? 1 : 0;
  if (jc == 0) {
    if (t < SINKN)   out[(size_t)bh * LKV + t] = 1;
    if (t < RECENTN) out[(size_t)bh * LKV + (LKV - RECENTN) + t] = 1;
  }
}

extern "C" void kernel_launch(void* const* d_in, const int* in_sizes, int n_in,
                              void* d_out, int out_size, void* d_ws, size_t ws_size,
                              hipStream_t stream) {
  const float* A = (const float*)d_in[0];
  int* out = (int*)d_out;

  // ws: spart[QCH*64*2048 f64]=8MB | epart[64*QCH*KVCH f64]
  double* spart = (double*)d_ws;
  double* epart = spart + (size_t)QCH * BH * LKV;

  stats_kernel<<<dim3(KVCH, QCH, BH), 256, 0, stream>>>(A, spart, epart);
  countmask_kernel<<<dim3(4, BH), 256, 0, stream>>>(spart, epart, out);
}

// Round 12
// 278.084 us; speedup vs baseline: 1.0860x; 1.0860x over previous
//
#include <hip/hip_runtime.h>

// (B,H,Lq,Lkv) = (2,32,2048,2048), KEEP_RATIO=0.5, SINK=4, RECENT=64, ALPHA=0.2
#define B_   2
#define H_   32
#define BH   64
#define LQ   2048
#define LKV  2048
#define SINKN   4
#define RECENTN 64
#define MID  1980                              // LKV - SINK - RECENT
#define TOTAL_BUDGET 30592                     // (1024-68)*32
#define MINB 198                               // int(1980*0.5*0.2)
#define QCH  4                                 // q-chunks
#define KVCH 2
#define KVLEN (LKV / KVCH)                     // 1024 cols per block
#define QLEN (LQ / QCH)                        // 512 rows per block
#define TROWS 4                                // rows per LDS tile
#define NT   (QLEN / TROWS)                    // 128 tiles
#define JW   495                               // MID/4, j-window per countmask block

// Native v_log_f32 (log2, ~2^-21 rel err) — accuracy-safe (R3-R11 all absmax 0).
static __device__ __forceinline__ float fast_log2(float x) {
#if defined(__has_builtin) && __has_builtin(__builtin_amdgcn_logf)
  return __builtin_amdgcn_logf(x);
#else
  float r; asm volatile("v_log_f32 %0, %1" : "=v"(r) : "v"(x)); return r;
#endif
}

// Issue one 4-row tile via global_load_lds (HBM -> LDS, no VGPR return).
// ldsbase is wave-uniform (HW adds lane*16B). One wave covers 1KB of each 4KB row.
static __device__ __forceinline__ void issue_tile(const float* base, int tile,
                                                  float* ldsbase, int laneoff) {
#pragma unroll
  for (int r = 0; r < TROWS; ++r) {
    const float* g = base + (size_t)(tile * TROWS + r) * LKV + laneoff;
    __builtin_amdgcn_global_load_lds(
        (const __attribute__((address_space(1))) void*)g,
        (__attribute__((address_space(3))) void*)(ldsbase + r * 1024),
        16, 0, 0);
  }
}

// Stats pass (measured best, R10: 278us total): block (kvc,qc,bh) covers
// 1024 cols x 512 rows; thread owns cols 4t..4t+3. HBM read goes through
// global_load_lds staging with a barrier-FREE double-buffered pipeline:
// wave w loads bytes [w*1024,(w+1)*1024) of each row-chunk and reads back
// exactly that quarter (col-map == lane-map), self-synced by counted vmcnt.
// f32 group-of-16-rows accumulation folded into f64, fixed order.
__global__ __launch_bounds__(256) void stats_kernel(const float* __restrict__ A,
                                                    double* __restrict__ spart,
                                                    double* __restrict__ epart) {
  const int kvc = blockIdx.x;     // 0..KVCH-1
  const int qc  = blockIdx.y;     // 0..QCH-1
  const int bh  = blockIdx.z;     // 0..63
  const int t   = threadIdx.x;    // 0..255
  const int w   = t >> 6;         // wave 0..3

  __shared__ float lbuf[2][TROWS][1024];   // 32 KB double buffer
  __shared__ double red[256];

  const float* base = A + ((size_t)bh * LQ + (size_t)qc * QLEN) * LKV + kvc * KVLEN;
  const int laneoff = 4 * t;                 // = w*256 + lane*4 floats
  float* ldsw0 = &lbuf[0][0][w * 256];       // wave-uniform dests
  float* ldsw1 = &lbuf[1][0][w * 256];

  double s0 = 0.0, s1 = 0.0, s2 = 0.0, s3 = 0.0, e = 0.0;
  float fs0 = 0.f, fs1 = 0.f, fs2 = 0.f, fs3 = 0.f;
  float fe0 = 0.f, fe1 = 0.f, fe2 = 0.f, fe3 = 0.f;

  issue_tile(base, 0, ldsw0, laneoff);
  int buf = 0;
  for (int tile = 0; tile < NT; ++tile) {
    if (tile + 1 < NT) {
      issue_tile(base, tile + 1, (buf ? ldsw0 : ldsw1), laneoff);
      asm volatile("s_waitcnt vmcnt(4)" ::: "memory");  // current tile's 4 loads done
    } else {
      asm volatile("s_waitcnt vmcnt(0)" ::: "memory");
    }
#pragma unroll
    for (int r = 0; r < TROWS; ++r) {
      float4 wv = *reinterpret_cast<const float4*>(&lbuf[buf][r][4 * t]);
      fs0 += wv.x; fs1 += wv.y; fs2 += wv.z; fs3 += wv.w;
      fe0 = fmaf(wv.x, fast_log2(wv.x + 1e-8f), fe0);
      fe1 = fmaf(wv.y, fast_log2(wv.y + 1e-8f), fe1);
      fe2 = fmaf(wv.z, fast_log2(wv.z + 1e-8f), fe2);
      fe3 = fmaf(wv.w, fast_log2(wv.w + 1e-8f), fe3);
    }
    if ((tile & 3) == 3) {  // every 16 rows: fold f32 -> f64 (fixed order)
      s0 += (double)fs0; s1 += (double)fs1; s2 += (double)fs2; s3 += (double)fs3;
      e += ((double)fe0 + (double)fe1) + ((double)fe2 + (double)fe3);
      fs0 = fs1 = fs2 = fs3 = 0.f;
      fe0 = fe1 = fe2 = fe3 = 0.f;
    }
    buf ^= 1;
  }

  double* sp = spart + (size_t)(qc * BH + bh) * LKV + kvc * KVLEN + 4 * t;
  sp[0] = s0; sp[1] = s1; sp[2] = s2; sp[3] = s3;

  red[t] = e;
  __syncthreads();
  for (int off = 128; off > 0; off >>= 1) {
    if (t < off) red[t] += red[t + off];
    __syncthreads();
  }
  if (t == 0) epart[(size_t)bh * (QCH * KVCH) + qc * KVCH + kvc] = red[0];
}

// Fused budget + reduce + stable-descending rank + mask write (2-launch pipeline).
// Block (jc, bh): redundantly computes its batch's budget allocation (exact
// _head_budgets semantics: half-even rint, Python floor-div), builds s[0..MID)
// in LDS (fixed-order f64 sum of QCH partials), then broadcast-only i-scan
// ranks 2 j-slots per thread. rank(j)=#{i: s_i>s_j}+#{i<j: s_i==s_j}.
__global__ __launch_bounds__(256) void countmask_kernel(const double* __restrict__ spart,
                                                        const double* __restrict__ epart,
                                                        int* __restrict__ out) {
  const int jc = blockIdx.x, bh = blockIdx.y, t = threadIdx.x;
  __shared__ double s[MID];
  __shared__ double he[H_];
  __shared__ int bud[H_];
  __shared__ int ksh;

  for (int m = t; m < MID; m += 256) {
    double v = 0.0;
    for (int qc = 0; qc < QCH; ++qc)
      v += spart[(size_t)(qc * BH + bh) * LKV + SINKN + m];
    s[m] = v;
  }
  const int b = bh >> 5;   // batch of this head
  if (t < H_) {
    double ss = 0.0;
    for (int p = 0; p < QCH * KVCH; ++p)
      ss += epart[(size_t)(b * H_ + t) * (QCH * KVCH) + p];
    he[t] = (-0.6931471805599453 * ss) / (double)LQ;
  }
  __syncthreads();
  if (t == 0) {
    double S = 0.0;
    for (int h = 0; h < H_; ++h) S += he[h];
    S += 1e-8;
    long long sum = 0;
    for (int h = 0; h < H_; ++h) {
      double x = he[h] / S * (double)TOTAL_BUDGET;
      int v = (int)rint(x);          // jnp.round = half-to-even
      if (v < MINB) v = MINB;
      bud[h] = v; sum += v;
    }
    long long diff = (long long)TOTAL_BUDGET - sum;
    long long ph = (diff >= 0) ? diff / H_ : -((-diff + H_ - 1) / H_);
    long long rem = diff - ph * H_;
    const int h = bh & 31;
    long long v = (long long)bud[h] + ph + ((h < rem) ? 1 : 0);
    if (v < 1) v = 1;
    if (v > MID) v = MID;
    ksh = (int)v;
  }
  __syncthreads();

  const int j0 = jc * JW + t;            // max 3*495+255 = 1740 < MID
  const int j1 = j0 + 256;               // valid if t < JW-256 = 239
  const bool has1 = (t < JW - 256);
  const double k0 = s[j0];
  const double k1 = has1 ? s[j1] : 0.0;
  unsigned c0 = 0, c1 = 0;
  for (int i = 0; i < MID; ++i) {
    const double si = s[i];
    c0 += (si > k0) ? 1u : 0u;
    c0 += ((si == k0) && (i < j0)) ? 1u : 0u;
    c1 += (si > k1) ? 1u : 0u;
    c1 += ((si == k1) && (i < j1)) ? 1u : 0u;
  }
  const unsigned k = (unsigned)ksh;
  out[(size_t)bh * LKV + SINKN + j0] = (c0 < k) ? 1 : 0;
  if (has1) out[(size_t)bh * LKV + SINKN + j1] = (c1 < k) ? 1 : 0;
  if (jc == 0) {
    if (t < SINKN)   out[(size_t)bh * LKV + t] = 1;
    if (t < RECENTN) out[(size_t)bh * LKV + (LKV - RECENTN) + t] = 1;
  }
}

extern "C" void kernel_launch(void* const* d_in, const int* in_sizes, int n_in,
                              void* d_out, int out_size, void* d_ws, size_t ws_size,
                              hipStream_t stream) {
  const float* A = (const float*)d_in[0];
  int* out = (int*)d_out;

  // ws: spart[QCH*64*2048 f64]=4MB | epart[64*QCH*KVCH f64]
  double* spart = (double*)d_ws;
  double* epart = spart + (size_t)QCH * BH * LKV;

  stats_kernel<<<dim3(KVCH, QCH, BH), 256, 0, stream>>>(A, spart, epart);
  countmask_kernel<<<dim3(4, BH), 256, 0, stream>>>(spart, epart, out);
}